// Round 15
// baseline (221.583 us; speedup 1.0000x reference)
//
#include <hip/hip_runtime.h>

// SegmentalEmotion: per-sample sliding-window segment means, two-phase.
// H: [B, T, D] f32, lengths_sec: [B] f32.
// Outputs (concat flat): S_pad [B, maxS, D] f32, mask [B, maxS] (0/1) f32.
//
// R5 -> R6: XCD swizzle was NULL (74-77us either way) -> ~3.8 TB/s ceiling is
// not a block-placement artifact. Halve LOGICAL bytes instead: segments start
// at s*hop (chunk-aligned) and win ~= 2*hop +/- 1, so with hop-row chunks
// seg_sum = P[s] + P[s+1] +/- at most ONE row. Phase 1 reads H exactly once
// (134 MB) into P[b,c,col] (d_ws); phase 2 combines (tiny).

#define D4 192  // D/4 float4 lanes per row (D == 768)

__device__ __forceinline__ void plan(double len, int T,
                                     long long& win, long long& hop) {
    double dur = (len < 0.001) ? 0.001 : len;
    double fps = (double)T / dur;
    win = (long long)rint(fps * 1.0);   // WIN_SEC = 1.0
    if (win < 1) win = 1;
    hop = (long long)rint(fps * 0.5);   // HOP_SEC = 0.5
    if (hop < 1) hop = 1;
}

// Phase 1: P[b, c, :] = sum of H rows [c*hop, min((c+1)*hop, T)).
__global__ __launch_bounds__(D4)
void chunk_sum_kernel(const float4* __restrict__ H4,
                      const float*  __restrict__ lens,
                      float4* __restrict__ P,
                      int T, int ncmax) {
    const int b   = blockIdx.x / ncmax;
    const int c   = blockIdx.x % ncmax;
    const int tid = threadIdx.x;

    long long win, hop;
    plan((double)lens[b], T, win, hop);
    const long long nc = ((long long)T + hop - 1) / hop;
    if (c >= nc) return;                       // unused slot (never read)

    const long long r0 = (long long)c * hop;
    long long r1 = r0 + hop;
    if (r1 > T) r1 = T;

    const float4* base = H4 + (size_t)b * T * D4 + tid;

    float ax = 0.f, ay = 0.f, az = 0.f, aw = 0.f;
    float bx = 0.f, by = 0.f, bz = 0.f, bw = 0.f;

    long long t = r0;
    for (; t + 8 <= r1; t += 8) {              // 8 loads in flight, contiguous rows
        float4 v0 = base[(t + 0) * D4];
        float4 v1 = base[(t + 1) * D4];
        float4 v2 = base[(t + 2) * D4];
        float4 v3 = base[(t + 3) * D4];
        float4 v4 = base[(t + 4) * D4];
        float4 v5 = base[(t + 5) * D4];
        float4 v6 = base[(t + 6) * D4];
        float4 v7 = base[(t + 7) * D4];
        ax += v0.x + v1.x + v2.x + v3.x;
        ay += v0.y + v1.y + v2.y + v3.y;
        az += v0.z + v1.z + v2.z + v3.z;
        aw += v0.w + v1.w + v2.w + v3.w;
        bx += v4.x + v5.x + v6.x + v7.x;
        by += v4.y + v5.y + v6.y + v7.y;
        bz += v4.z + v5.z + v6.z + v7.z;
        bw += v4.w + v5.w + v6.w + v7.w;
    }
    for (; t < r1; ++t) {
        float4 v = base[t * D4];
        ax += v.x; ay += v.y; az += v.z; aw += v.w;
    }

    P[((size_t)b * ncmax + c) * D4 + tid] =
        make_float4(ax + bx, ay + by, az + bz, aw + bw);
}

// Phase 2: combine chunk sums (+/- at most one H row) into segment means.
__global__ __launch_bounds__(D4)
void seg_out_kernel(const float4* __restrict__ H4,
                    const float*  __restrict__ lens,
                    const float4* __restrict__ P,
                    float4* __restrict__ S4,
                    float*  __restrict__ M,
                    int T, int maxS, int ncmax) {
    const int b   = blockIdx.x / maxS;
    const int s   = blockIdx.x % maxS;
    const int tid = threadIdx.x;

    long long win, hop;
    plan((double)lens[b], T, win, hop);
    const long long n = ((long long)T >= win) ? (((long long)T - win) / hop + 1) : 0;
    const bool fallback = (n == 0);
    const long long n_eff = fallback ? 1 : n;

    if (tid == 0) M[(size_t)b * maxS + s] = (s < n_eff) ? 1.0f : 0.0f;

    float4* out = S4 + ((size_t)b * maxS + s) * D4;
    if (s >= n_eff) { out[tid] = make_float4(0.f, 0.f, 0.f, 0.f); return; }

    const float4* Pb = P + (size_t)b * ncmax * D4;
    const float4* Hb = H4 + (size_t)b * T * D4 + tid;

    float ax, ay, az, aw;
    long long cnt;

    if (fallback) {                            // single mean over all T rows
        const long long nc = ((long long)T + hop - 1) / hop;
        ax = ay = az = aw = 0.f;
        for (long long c = 0; c < nc; ++c) {
            float4 p = Pb[c * D4 + tid];
            ax += p.x; ay += p.y; az += p.z; aw += p.w;
        }
        cnt = T;
    } else {
        const long long start = (long long)s * hop;
        const long long end   = start + win;   // <= T guaranteed for s < n
        float4 p = Pb[(size_t)s * D4 + tid];
        ax = p.x; ay = p.y; az = p.z; aw = p.w;
        const long long pos = (s + 1) * hop;   // end of chunk s
        if (pos < end) {                       // tail into chunk s+1 (win > hop)
            float4 q = Pb[(size_t)(s + 1) * D4 + tid];
            ax += q.x; ay += q.y; az += q.z; aw += q.w;
            long long e1 = (s + 2) * hop;      // end of chunk s+1
            if (e1 > T) e1 = T;
            for (long long r = end; r < e1; ++r) {   // over-covered: subtract (<=1 row)
                float4 v = Hb[r * D4];
                ax -= v.x; ay -= v.y; az -= v.z; aw -= v.w;
            }
            for (long long r = e1; r < end; ++r) {   // under-covered: add (<=1 row)
                float4 v = Hb[r * D4];
                ax += v.x; ay += v.y; az += v.z; aw += v.w;
            }
        }
        cnt = win;
    }

    const float c = (float)cnt;
    out[tid] = make_float4(ax / c, ay / c, az / c, aw / c);
}

extern "C" void kernel_launch(void* const* d_in, const int* in_sizes, int n_in,
                              void* d_out, int out_size, void* d_ws, size_t ws_size,
                              hipStream_t stream) {
    const float* H    = (const float*)d_in[0];
    const float* lens = (const float*)d_in[1];

    const int B = in_sizes[1];                 // 32
    const int D = 768;
    const int T = in_sizes[0] / (B * D);       // 1500
    const int maxS = out_size / (B * (D + 1)); // out = B*maxS*D + B*maxS

    // nc = ceil(T/hop) <= n + 3 <= maxS + 3 (win ~= 2*hop)
    const int ncmax = maxS + 3;

    float* S = (float*)d_out;
    float* M = S + (size_t)B * maxS * D;
    float4* P = (float4*)d_ws;                 // B * ncmax * D4 float4 = ~6.1 MB

    chunk_sum_kernel<<<dim3(B * ncmax), D4, 0, stream>>>(
        (const float4*)H, lens, P, T, ncmax);
    seg_out_kernel<<<dim3(B * maxS), D4, 0, stream>>>(
        (const float4*)H, lens, P, (float4*)S, M, T, maxS, ncmax);
}